// Round 4
// baseline (568.585 us; speedup 1.0000x reference)
//
#include <hip/hip_runtime.h>
#include <hip/hip_bf16.h>

typedef __bf16 bf16_t;
typedef __bf16 bf16x8 __attribute__((ext_vector_type(8)));
typedef float f32x4 __attribute__((ext_vector_type(4)));

__device__ __forceinline__ float gelu_f(float x) {
    // jax.nn.gelu default: tanh approximation
    float u = 0.7978845608028654f * (x + 0.044715f * x * x * x);
    float e = __expf(2.0f * u);
    float t = 1.0f - 2.0f / (e + 1.0f);   // tanh(u), safe at +-inf
    return 0.5f * x * (1.0f + t);
}

// ---------------------------------------------------------------------------
// Dtype detect: x is either f32 (low 16 bits of each word = uniform mantissa
// bits) or packed bf16 (low 16 bits = a bf16 whose exponent byte, bits 14:7,
// is concentrated near 0x7F for N(0,1) data). Count in-range exponents over
// 256 words: bf16 ~> 250, f32 ~> 40. flag: 1 = bf16, 0 = f32.
// ---------------------------------------------------------------------------
__global__ void detect_kernel(const unsigned int* __restrict__ xw,
                              int* __restrict__ flagp)
{
    __shared__ int cnt;
    int tid = threadIdx.x;
    if (tid == 0) cnt = 0;
    __syncthreads();
    unsigned int w = xw[tid];
    int le = (w >> 7) & 0xFF;
    int ok = (le >= 0x60 && le <= 0x88) ? 1 : 0;
    atomicAdd(&cnt, ok);
    __syncthreads();
    if (tid == 0) *flagp = (cnt >= 128) ? 1 : 0;
}

__device__ __forceinline__ float rd_elem(const void* p, size_t idx, int isbf) {
    return isbf ? (float)((const bf16_t*)p)[idx] : ((const float*)p)[idx];
}

// ---------------------------------------------------------------------------
// Weight pack -> bf16 B^T ([N,K] row-major) copies in workspace.
//  W1t [2048][512], W2t [512][2048], Wat [1024][512] (col j: gate g=j>>9,
//  e=(j&511)>>6, h=j&63), Wbt [512][1024].
// ---------------------------------------------------------------------------
__global__ __launch_bounds__(256) void pack_kernel(
    const void* __restrict__ W1, const void* __restrict__ W2,
    const void* __restrict__ Wa1, const void* __restrict__ Wa2,
    const void* __restrict__ Wb1, const void* __restrict__ Wb2,
    const int* __restrict__ flagp,
    bf16_t* __restrict__ W1t, bf16_t* __restrict__ W2t,
    bf16_t* __restrict__ Wat, bf16_t* __restrict__ Wbt)
{
    const int isbf = *flagp;
    int i = blockIdx.x * 256 + threadIdx.x;
    if (i < 1048576) {                       // W1t[n][k] = W1[k][n], [512,2048]
        int n = i >> 9, k = i & 511;
        W1t[i] = (bf16_t)rd_elem(W1, (size_t)k * 2048 + n, isbf);
    } else if (i < 2097152) {                // W2t[n][k] = W2[k][n], [2048,512]
        int j = i - 1048576;
        int n = j >> 11, k = j & 2047;
        W2t[j] = (bf16_t)rd_elem(W2, (size_t)k * 512 + n, isbf);
    } else if (i < 2621440) {                // Wat[n][d] = Wa_g[e][d][h]
        int j = i - 2097152;
        int n = j >> 9, d = j & 511;
        const void* Wa = (n < 512) ? Wa1 : Wa2;
        int nn = n & 511, e = nn >> 6, hh = nn & 63;
        Wat[j] = (bf16_t)rd_elem(Wa, ((size_t)e * 512 + d) * 64 + hh, isbf);
    } else {                                 // Wbt[dout][k] = Wb_g[e][h][dout]
        int j = i - 2621440;
        int d = j >> 10, n = j & 1023;
        const void* Wb = (n < 512) ? Wb1 : Wb2;
        int nn = n & 511;
        Wbt[j] = (bf16_t)rd_elem(Wb, (size_t)nn * 512 + d, isbf);
    }
}

// ---------------------------------------------------------------------------
// Gate: masked token r in [0,16384), token = (r>>12)*8192 + 4096 + (r&4095).
// Both routers' logits (E=8 each), top-2 softmax, dense w[16] fp32.
// ---------------------------------------------------------------------------
__global__ __launch_bounds__(256) void gate_kernel(
    const void* __restrict__ xv,
    const void* __restrict__ Wg1, const void* __restrict__ Wg2,
    const int* __restrict__ flagp,
    float* __restrict__ wout)
{
    __shared__ float WgL[2][4096];   // [512][8] each, f32
    const int isbf = *flagp;
    const int tid = threadIdx.x;
    const int wave = tid >> 6, lane = tid & 63;
    for (int i = tid; i < 4096; i += 256) {
        WgL[0][i] = rd_elem(Wg1, i, isbf);
        WgL[1][i] = rd_elem(Wg2, i, isbf);
    }
    __syncthreads();

    for (int it = 0; it < 16; ++it) {
        int r = blockIdx.x * 64 + it * 4 + wave;
        int t = (r >> 12) * 8192 + 4096 + (r & 4095);
        float xr[8];
        if (isbf) {
            bf16x8 t8 = *(const bf16x8*)((const bf16_t*)xv + (size_t)t * 512 + lane * 8);
#pragma unroll
            for (int j = 0; j < 8; ++j) xr[j] = (float)t8[j];
        } else {
            const float* xp = (const float*)xv + (size_t)t * 512 + lane * 8;
            float4 u0 = *(const float4*)xp;
            float4 u1 = *(const float4*)(xp + 4);
            xr[0] = u0.x; xr[1] = u0.y; xr[2] = u0.z; xr[3] = u0.w;
            xr[4] = u1.x; xr[5] = u1.y; xr[6] = u1.z; xr[7] = u1.w;
        }
        float a[16];
#pragma unroll
        for (int e = 0; e < 16; ++e) a[e] = 0.0f;
#pragma unroll
        for (int j = 0; j < 8; ++j) {
            float xj = xr[j];
            int d = lane * 8 + j;
            const float* w1r = &WgL[0][d * 8];
            const float* w2r = &WgL[1][d * 8];
#pragma unroll
            for (int e = 0; e < 8; ++e) {
                a[e]     += xj * w1r[e];
                a[8 + e] += xj * w2r[e];
            }
        }
#pragma unroll
        for (int e = 0; e < 16; ++e) {
            a[e] += __shfl_xor(a[e], 32, 64);
            a[e] += __shfl_xor(a[e], 16, 64);
            a[e] += __shfl_xor(a[e], 8, 64);
            a[e] += __shfl_xor(a[e], 4, 64);
            a[e] += __shfl_xor(a[e], 2, 64);
            a[e] += __shfl_xor(a[e], 1, 64);
        }
        if (lane == 0) {
#pragma unroll
            for (int g = 0; g < 2; ++g) {
                float v0 = -1e30f, v1 = -1e30f;
                int i0 = 0, i1 = 0;
#pragma unroll
                for (int e = 0; e < 8; ++e) {
                    float vv = a[g * 8 + e];
                    if (vv > v0) { v0 = vv; i0 = e; }
                }
#pragma unroll
                for (int e = 0; e < 8; ++e) {
                    float vv = a[g * 8 + e];
                    if (e != i0 && vv > v1) { v1 = vv; i1 = e; }
                }
                float e1 = __expf(v1 - v0);
                float p0 = 1.0f / (1.0f + e1);
                float p1 = 1.0f - p0;
#pragma unroll
                for (int e = 0; e < 8; ++e)
                    wout[(size_t)r * 16 + g * 8 + e] =
                        (e == i0) ? p0 : ((e == i1) ? p1 : 0.0f);
            }
        }
    }
}

// ---------------------------------------------------------------------------
// GEMM: C = epilogue(A @ Bt^T). 128x128 tile, BK=32, 4 waves x (64x64 via
// 4x4 of 16x16x32 bf16 MFMA). Conservative staging: vector global load ->
// ds_write_b128 (no global_load_lds this round).
// EPI: 0 = +bias, store to out (flag dtype)        [FFN2]
//      1 = gelu(+bias), store bf16                 [FFN1]
//      2 = gelu * wgt[grow*16+(col>>6)], bf16      [MoE up]
//      3 = +=C masked (row&8191)>=id, out (flag)   [MoE down]
// A dtype: EPI 1,2 read x (flag dtype); EPI 0,3 read bf16 ws.
// ROWMAP: 0 identity(+off); 1 A-rows tokenmapped; 2 C-rows tokenmapped.
// ---------------------------------------------------------------------------
template <int EPI, int ROWMAP>
__global__ __launch_bounds__(256, 2) void gemm_kernel(
    const void* __restrict__ Av, int lda,
    const bf16_t* __restrict__ Bt, int ldb,
    void* __restrict__ Cv, int ldc, int K,
    int off1, int off2,
    const void* __restrict__ biasv,
    const float* __restrict__ wgt,
    const int* __restrict__ id_ptr,
    const int* __restrict__ flagp)
{
    constexpr bool ADT = (EPI == 1 || EPI == 2);   // A = x, dtype per flag
    __shared__ __align__(16) bf16_t As[128 * 32];  // 8 KB
    __shared__ __align__(16) bf16_t Bs[128 * 32];

    const int isbf = *flagp;
    const int tid = threadIdx.x;
    const int lane = tid & 63;
    const int wave = tid >> 6;
    const int wm = wave >> 1, wn = wave & 1;
    const int ln15 = lane & 15, lg = lane >> 4;

    const int r0 = blockIdx.x * 128;
    const int c0 = blockIdx.y * 128;
    int rA0, rC0, grow0;
    if (ROWMAP == 0) {
        rA0 = off1 + r0; rC0 = off2 + r0; grow0 = 0;
    } else if (ROWMAP == 1) {
        int g = off1 + r0;
        rA0 = (g >> 12) * 8192 + 4096 + (g & 4095);
        rC0 = r0; grow0 = g;
    } else {
        int g = off1 + r0;
        rA0 = r0; grow0 = 0;
        rC0 = (g >> 12) * 8192 + 4096 + (g & 4095);
    }

    const bf16_t* Ab = (const bf16_t*)Av;
    const float*  Af = (const float*)Av;

    f32x4 acc[4][4];
#pragma unroll
    for (int r = 0; r < 4; ++r)
#pragma unroll
        for (int c = 0; c < 4; ++c)
            acc[r][c] = (f32x4){0.f, 0.f, 0.f, 0.f};

    const int nK = K >> 5;
    for (int kt = 0; kt < nK; ++kt) {
        const int k0 = kt * 32;
        // 512 chunks of 8 elems per matrix; chunk c: row c>>2, elems (c&3)*8.
#pragma unroll
        for (int i = 0; i < 2; ++i) {
            int chunk = i * 256 + tid;
            int row = chunk >> 2;
            int col = (chunk & 3) * 8;
            bf16x8 av;
            if (ADT && !isbf) {
                const float* s = Af + (size_t)(rA0 + row) * lda + (k0 + col);
                float4 u0 = *(const float4*)s;
                float4 u1 = *(const float4*)(s + 4);
                av[0] = (bf16_t)u0.x; av[1] = (bf16_t)u0.y;
                av[2] = (bf16_t)u0.z; av[3] = (bf16_t)u0.w;
                av[4] = (bf16_t)u1.x; av[5] = (bf16_t)u1.y;
                av[6] = (bf16_t)u1.z; av[7] = (bf16_t)u1.w;
            } else {
                av = *(const bf16x8*)(Ab + (size_t)(rA0 + row) * lda + (k0 + col));
            }
            *(bf16x8*)((char*)As + (size_t)chunk * 16) = av;
            bf16x8 bv = *(const bf16x8*)(Bt + (size_t)(c0 + row) * ldb + (k0 + col));
            *(bf16x8*)((char*)Bs + (size_t)chunk * 16) = bv;
        }
        __syncthreads();

        bf16x8 af[4], bfr[4];
#pragma unroll
        for (int r = 0; r < 4; ++r)
            af[r] = *(const bf16x8*)(As + ((wm * 64 + r * 16 + ln15) * 32 + lg * 8));
#pragma unroll
        for (int c = 0; c < 4; ++c)
            bfr[c] = *(const bf16x8*)(Bs + ((wn * 64 + c * 16 + ln15) * 32 + lg * 8));
#pragma unroll
        for (int r = 0; r < 4; ++r)
#pragma unroll
            for (int c = 0; c < 4; ++c)
                acc[r][c] = __builtin_amdgcn_mfma_f32_16x16x32_bf16(
                    af[r], bfr[c], acc[r][c], 0, 0, 0);
        __syncthreads();
    }

    const int idv = (EPI == 3) ? id_ptr[0] : 0;
    bf16_t* Cb = (bf16_t*)Cv;
    float*  Cf = (float*)Cv;

#pragma unroll
    for (int r = 0; r < 4; ++r) {
#pragma unroll
        for (int v = 0; v < 4; ++v) {
            int lrow = wm * 64 + r * 16 + lg * 4 + v;   // tile-local row
            int crow = rC0 + lrow;
#pragma unroll
            for (int c = 0; c < 4; ++c) {
                int col = c0 + wn * 64 + c * 16 + ln15;
                float val = acc[r][c][v];
                size_t oidx = (size_t)crow * ldc + col;
                if (EPI == 0) {
                    if (biasv) val += rd_elem(biasv, col, isbf);
                    if (isbf) Cb[oidx] = (bf16_t)val; else Cf[oidx] = val;
                } else if (EPI == 1) {
                    if (biasv) val += rd_elem(biasv, col, isbf);
                    Cb[oidx] = (bf16_t)gelu_f(val);
                } else if (EPI == 2) {
                    val = gelu_f(val) * wgt[(size_t)(grow0 + lrow) * 16 + (col >> 6)];
                    Cb[oidx] = (bf16_t)val;
                } else {  // EPI == 3
                    if ((crow & 8191) >= idv) {
                        if (isbf) Cb[oidx] = (bf16_t)((float)Cb[oidx] + val);
                        else      Cf[oidx] = Cf[oidx] + val;
                    }
                }
            }
        }
    }
}

// ---------------------------------------------------------------------------
extern "C" void kernel_launch(void* const* d_in, const int* in_sizes, int n_in,
                              void* d_out, int out_size, void* d_ws, size_t ws_size,
                              hipStream_t stream)
{
    const void* x   = d_in[0];
    const int*  idp = (const int*)d_in[1];
    const void* W1  = d_in[2];
    const void* b1  = d_in[3];
    const void* W2  = d_in[4];
    const void* b2  = d_in[5];
    const void* Wg1 = d_in[6];
    const void* Wa1 = d_in[7];
    const void* Wb1 = d_in[8];
    const void* Wg2 = d_in[9];
    const void* Wa2 = d_in[10];
    const void* Wb2 = d_in[11];

    char* p = (char*)d_ws;
    bf16_t* W1t  = (bf16_t*)(p);                 // 2 MB
    bf16_t* W2t  = (bf16_t*)(p + 2097152);       // 2 MB
    bf16_t* Wat  = (bf16_t*)(p + 4194304);       // 1 MB
    bf16_t* Wbt  = (bf16_t*)(p + 5242880);       // 1 MB
    float*  wbuf = (float*) (p + 6291456);       // 1 MB
    int*    flagp= (int*)   (p + 7340032);       // 64 KB slot
    bf16_t* big  = (bf16_t*)(p + 7405568);

    const size_t base = 7405568ull;
    size_t cap = (ws_size > base) ? ws_size - base : 0;
    int Mc = 32768;                               // FFN h chunk [Mc,2048] bf16
    while ((size_t)Mc * 4096ull > cap && Mc > 128) Mc >>= 1;
    int Mcm = 16384;                              // MoE h chunk [Mcm,1024] bf16
    while ((size_t)Mcm * 2048ull > cap && Mcm > 128) Mcm >>= 1;

    detect_kernel<<<1, 256, 0, stream>>>((const unsigned int*)x, flagp);
    pack_kernel<<<12288, 256, 0, stream>>>(W1, W2, Wa1, Wa2, Wb1, Wb2, flagp,
                                           W1t, W2t, Wat, Wbt);
    gate_kernel<<<256, 256, 0, stream>>>(x, Wg1, Wg2, flagp, wbuf);

    // FFN, chunked over rows: out[m:m+Mc] = gelu(x@W1+b1)@W2 + b2
    for (int m = 0; m < 32768; m += Mc) {
        gemm_kernel<1, 0><<<dim3(Mc / 128, 16), 256, 0, stream>>>(
            x, 512, W1t, 512, big, 2048, 512, m, 0,
            b1, nullptr, nullptr, flagp);
        gemm_kernel<0, 0><<<dim3(Mc / 128, 4), 256, 0, stream>>>(
            big, 2048, W2t, 2048, d_out, 512, 2048, 0, m,
            b2, nullptr, nullptr, flagp);
    }
    // MoE, chunked over masked rows: out[map(g)] += (gelu(x@Wa)*w)@Wb
    for (int m = 0; m < 16384; m += Mcm) {
        gemm_kernel<2, 1><<<dim3(Mcm / 128, 8), 256, 0, stream>>>(
            x, 512, Wat, 512, big, 1024, 512, m, 0,
            nullptr, wbuf, nullptr, flagp);
        gemm_kernel<3, 2><<<dim3(Mcm / 128, 4), 256, 0, stream>>>(
            big, 1024, Wbt, 1024, d_out, 512, 1024, m, 0,
            nullptr, nullptr, idp, flagp);
    }
}

// Round 7
// 517.197 us; speedup vs baseline: 1.0994x; 1.0994x over previous
//
#include <hip/hip_runtime.h>
#include <hip/hip_bf16.h>

typedef __bf16 bf16_t;
typedef __bf16 bf16x8 __attribute__((ext_vector_type(8)));
typedef float f32x4 __attribute__((ext_vector_type(4)));

#define AS1 __attribute__((address_space(1)))
#define AS3 __attribute__((address_space(3)))

__device__ __forceinline__ void gload_lds16(const void* g, void* l) {
    __builtin_amdgcn_global_load_lds((const AS1 void*)g, (AS3 void*)l, 16, 0, 0);
}

__device__ __forceinline__ float gelu_f(float x) {
    // jax.nn.gelu default: tanh approximation
    float u = 0.7978845608028654f * (x + 0.044715f * x * x * x);
    float e = __expf(2.0f * u);
    float t = 1.0f - 2.0f / (e + 1.0f);   // tanh(u), safe at +-inf
    return 0.5f * x * (1.0f + t);
}

// ---------------------------------------------------------------------------
// Dtype detect (validated R4): low-16 exponent-field concentration test.
// flag: 1 = bf16-packed inputs, 0 = f32 inputs. (R4 evidence: f32.)
// ---------------------------------------------------------------------------
__global__ void detect_kernel(const unsigned int* __restrict__ xw,
                              int* __restrict__ flagp)
{
    __shared__ int cnt;
    int tid = threadIdx.x;
    if (tid == 0) cnt = 0;
    __syncthreads();
    unsigned int w = xw[tid];
    int le = (w >> 7) & 0xFF;
    int ok = (le >= 0x60 && le <= 0x88) ? 1 : 0;
    atomicAdd(&cnt, ok);
    __syncthreads();
    if (tid == 0) *flagp = (cnt >= 128) ? 1 : 0;
}

__device__ __forceinline__ float rd_elem(const void* p, size_t idx, int isbf) {
    return isbf ? (float)((const bf16_t*)p)[idx] : ((const float*)p)[idx];
}

// ---------------------------------------------------------------------------
// Convert x -> bf16 xb [32768*512]. One 8-elem chunk per thread.
// ---------------------------------------------------------------------------
__global__ __launch_bounds__(256) void convert_kernel(
    const void* __restrict__ x, const int* __restrict__ flagp,
    bf16_t* __restrict__ xb)
{
    const int isbf = *flagp;
    size_t i = (size_t)blockIdx.x * 256 + threadIdx.x;   // chunk id, 2097152 total
    if (isbf) {
        ((bf16x8*)xb)[i] = ((const bf16x8*)x)[i];
    } else {
        const float* s = (const float*)x + i * 8;
        float4 u0 = *(const float4*)s;
        float4 u1 = *(const float4*)(s + 4);
        bf16x8 v;
        v[0] = (bf16_t)u0.x; v[1] = (bf16_t)u0.y;
        v[2] = (bf16_t)u0.z; v[3] = (bf16_t)u0.w;
        v[4] = (bf16_t)u1.x; v[5] = (bf16_t)u1.y;
        v[6] = (bf16_t)u1.z; v[7] = (bf16_t)u1.w;
        ((bf16x8*)xb)[i] = v;
    }
}

// ---------------------------------------------------------------------------
// Weight pack -> bf16 B^T ([N,K] row-major) copies in workspace.
//  W1t [2048][512], W2t [512][2048], Wat [1024][512], Wbt [512][1024].
// ---------------------------------------------------------------------------
__global__ __launch_bounds__(256) void pack_kernel(
    const void* __restrict__ W1, const void* __restrict__ W2,
    const void* __restrict__ Wa1, const void* __restrict__ Wa2,
    const void* __restrict__ Wb1, const void* __restrict__ Wb2,
    const int* __restrict__ flagp,
    bf16_t* __restrict__ W1t, bf16_t* __restrict__ W2t,
    bf16_t* __restrict__ Wat, bf16_t* __restrict__ Wbt)
{
    const int isbf = *flagp;
    int i = blockIdx.x * 256 + threadIdx.x;
    if (i < 1048576) {                       // W1t[n][k] = W1[k][n], [512,2048]
        int n = i >> 9, k = i & 511;
        W1t[i] = (bf16_t)rd_elem(W1, (size_t)k * 2048 + n, isbf);
    } else if (i < 2097152) {                // W2t[n][k] = W2[k][n], [2048,512]
        int j = i - 1048576;
        int n = j >> 11, k = j & 2047;
        W2t[j] = (bf16_t)rd_elem(W2, (size_t)k * 512 + n, isbf);
    } else if (i < 2621440) {                // Wat[n][d] = Wa_g[e][d][h]
        int j = i - 2097152;
        int n = j >> 9, d = j & 511;
        const void* Wa = (n < 512) ? Wa1 : Wa2;
        int nn = n & 511, e = nn >> 6, hh = nn & 63;
        Wat[j] = (bf16_t)rd_elem(Wa, ((size_t)e * 512 + d) * 64 + hh, isbf);
    } else {                                 // Wbt[dout][k] = Wb_g[e][h][dout]
        int j = i - 2621440;
        int d = j >> 10, n = j & 1023;
        const void* Wb = (n < 512) ? Wb1 : Wb2;
        int nn = n & 511;
        Wbt[j] = (bf16_t)rd_elem(Wb, (size_t)nn * 512 + d, isbf);
    }
}

// ---------------------------------------------------------------------------
// Gate: masked token r in [0,16384), token = (r>>12)*8192 + 4096 + (r&4095).
// CRITICAL (R5/R6 post-mortem): logits MUST be computed from x at source
// precision (f32 path), NOT from bf16 xb — top-2 selection is discontinuous;
// bf16-rounded logits flip near-tied expert choices vs the reference
// (absmax 1.96, deterministic). R4's f32 gate passed at 0.031.
// ---------------------------------------------------------------------------
__global__ __launch_bounds__(256) void gate_kernel(
    const void* __restrict__ xv,
    const void* __restrict__ Wg1, const void* __restrict__ Wg2,
    const int* __restrict__ flagp,
    float* __restrict__ wout)
{
    __shared__ float WgL[2][4096];   // [512][8] each, f32
    const int isbf = *flagp;
    const int tid = threadIdx.x;
    const int wave = tid >> 6, lane = tid & 63;
    for (int i = tid; i < 4096; i += 256) {
        WgL[0][i] = rd_elem(Wg1, i, isbf);
        WgL[1][i] = rd_elem(Wg2, i, isbf);
    }
    __syncthreads();

    for (int it = 0; it < 16; ++it) {
        int r = blockIdx.x * 64 + it * 4 + wave;
        int t = (r >> 12) * 8192 + 4096 + (r & 4095);
        float xr[8];
        if (isbf) {
            bf16x8 t8 = *(const bf16x8*)((const bf16_t*)xv + (size_t)t * 512 + lane * 8);
#pragma unroll
            for (int j = 0; j < 8; ++j) xr[j] = (float)t8[j];
        } else {
            const float* xp = (const float*)xv + (size_t)t * 512 + lane * 8;
            float4 u0 = *(const float4*)xp;
            float4 u1 = *(const float4*)(xp + 4);
            xr[0] = u0.x; xr[1] = u0.y; xr[2] = u0.z; xr[3] = u0.w;
            xr[4] = u1.x; xr[5] = u1.y; xr[6] = u1.z; xr[7] = u1.w;
        }
        float a[16];
#pragma unroll
        for (int e = 0; e < 16; ++e) a[e] = 0.0f;
#pragma unroll
        for (int j = 0; j < 8; ++j) {
            float xj = xr[j];
            int d = lane * 8 + j;
            const float* w1r = &WgL[0][d * 8];
            const float* w2r = &WgL[1][d * 8];
#pragma unroll
            for (int e = 0; e < 8; ++e) {
                a[e]     += xj * w1r[e];
                a[8 + e] += xj * w2r[e];
            }
        }
#pragma unroll
        for (int e = 0; e < 16; ++e) {
            a[e] += __shfl_xor(a[e], 32, 64);
            a[e] += __shfl_xor(a[e], 16, 64);
            a[e] += __shfl_xor(a[e], 8, 64);
            a[e] += __shfl_xor(a[e], 4, 64);
            a[e] += __shfl_xor(a[e], 2, 64);
            a[e] += __shfl_xor(a[e], 1, 64);
        }
        if (lane == 0) {
#pragma unroll
            for (int g = 0; g < 2; ++g) {
                float v0 = -1e30f, v1 = -1e30f;
                int i0 = 0, i1 = 0;
#pragma unroll
                for (int e = 0; e < 8; ++e) {
                    float vv = a[g * 8 + e];
                    if (vv > v0) { v0 = vv; i0 = e; }
                }
#pragma unroll
                for (int e = 0; e < 8; ++e) {
                    float vv = a[g * 8 + e];
                    if (e != i0 && vv > v1) { v1 = vv; i1 = e; }
                }
                float e1 = __expf(v1 - v0);
                float p0 = 1.0f / (1.0f + e1);
                float p1 = 1.0f - p0;
#pragma unroll
                for (int e = 0; e < 8; ++e)
                    wout[(size_t)r * 16 + g * 8 + e] =
                        (e == i0) ? p0 : ((e == i1) ? p1 : 0.0f);
            }
        }
    }
}

// ---------------------------------------------------------------------------
// GEMM: C = epilogue(A @ Bt^T), A/Bt bf16. 128x128 tile, BK=32, 4 waves x
// (64x64 via 4x4 of 16x16x32 bf16 MFMA). Full global_load_lds(16B) staging
// (exonerated by R5/R6 bisection: error invariant to staging mechanism),
// ds_read_b128 fragments.
// EPI: 0 = +bias, store out (flag dtype)   [FFN2]
//      1 = gelu(+bias), bf16               [FFN1]
//      2 = gelu * wgt[grow*16+(col>>6)]    [MoE up]
//      3 = +=C masked (row&8191)>=id       [MoE down]
// ROWMAP: 0 identity(+off); 1 A-rows tokenmapped; 2 C-rows tokenmapped.
// ---------------------------------------------------------------------------
template <int EPI, int ROWMAP>
__global__ __launch_bounds__(256, 2) void gemm_kernel(
    const bf16_t* __restrict__ A, int lda,
    const bf16_t* __restrict__ Bt, int ldb,
    void* __restrict__ Cv, int ldc, int K,
    int off1, int off2,
    const void* __restrict__ biasv,
    const float* __restrict__ wgt,
    const int* __restrict__ id_ptr,
    const int* __restrict__ flagp)
{
    __shared__ __align__(16) bf16_t As[128 * 32];  // 8 KB = 512 x 16B chunks
    __shared__ __align__(16) bf16_t Bs[128 * 32];

    const int isbf = *flagp;
    const int tid = threadIdx.x;
    const int lane = tid & 63;
    const int wave = tid >> 6;
    const int wm = wave >> 1, wn = wave & 1;
    const int ln15 = lane & 15, lg = lane >> 4;

    const int r0 = blockIdx.x * 128;
    const int c0 = blockIdx.y * 128;
    int rA0, rC0, grow0;
    if (ROWMAP == 0) {
        rA0 = off1 + r0; rC0 = off2 + r0; grow0 = 0;
    } else if (ROWMAP == 1) {
        int g = off1 + r0;
        rA0 = (g >> 12) * 8192 + 4096 + (g & 4095);
        rC0 = r0; grow0 = g;
    } else {
        int g = off1 + r0;
        rA0 = r0; grow0 = 0;
        rC0 = (g >> 12) * 8192 + 4096 + (g & 4095);
    }

    f32x4 acc[4][4];
#pragma unroll
    for (int r = 0; r < 4; ++r)
#pragma unroll
        for (int c = 0; c < 4; ++c)
            acc[r][c] = (f32x4){0.f, 0.f, 0.f, 0.f};

    const int nK = K >> 5;
    for (int kt = 0; kt < nK; ++kt) {
        const int k0 = kt * 32;
        // chunk c = i*256+tid: row c>>2, elems (c&3)*8..+7 -> LDS bytes c*16.
        // LDS dst: wave-uniform base (i*256+wave*64)*16; HW adds lane*16.
#pragma unroll
        for (int i = 0; i < 2; ++i) {
            int chunk = i * 256 + tid;
            int row = chunk >> 2;
            int col = (chunk & 3) * 8;
            gload_lds16(A + (size_t)(rA0 + row) * lda + (k0 + col),
                        (char*)As + (i * 256 + wave * 64) * 16);
            gload_lds16(Bt + (size_t)(c0 + row) * ldb + (k0 + col),
                        (char*)Bs + (i * 256 + wave * 64) * 16);
        }
        __builtin_amdgcn_s_waitcnt(0);
        __syncthreads();

        bf16x8 af[4], bfr[4];
#pragma unroll
        for (int r = 0; r < 4; ++r)
            af[r] = *(const bf16x8*)(As + ((wm * 64 + r * 16 + ln15) * 32 + lg * 8));
#pragma unroll
        for (int c = 0; c < 4; ++c)
            bfr[c] = *(const bf16x8*)(Bs + ((wn * 64 + c * 16 + ln15) * 32 + lg * 8));
#pragma unroll
        for (int r = 0; r < 4; ++r)
#pragma unroll
            for (int c = 0; c < 4; ++c)
                acc[r][c] = __builtin_amdgcn_mfma_f32_16x16x32_bf16(
                    af[r], bfr[c], acc[r][c], 0, 0, 0);
        __syncthreads();
    }

    const int idv = (EPI == 3) ? id_ptr[0] : 0;
    bf16_t* Cb = (bf16_t*)Cv;
    float*  Cf = (float*)Cv;

#pragma unroll
    for (int r = 0; r < 4; ++r) {
#pragma unroll
        for (int v = 0; v < 4; ++v) {
            int lrow = wm * 64 + r * 16 + lg * 4 + v;   // tile-local row
            int crow = rC0 + lrow;
#pragma unroll
            for (int c = 0; c < 4; ++c) {
                int col = c0 + wn * 64 + c * 16 + ln15;
                float val = acc[r][c][v];
                size_t oidx = (size_t)crow * ldc + col;
                if (EPI == 0) {
                    if (biasv) val += rd_elem(biasv, col, isbf);
                    if (isbf) Cb[oidx] = (bf16_t)val; else Cf[oidx] = val;
                } else if (EPI == 1) {
                    if (biasv) val += rd_elem(biasv, col, isbf);
                    Cb[oidx] = (bf16_t)gelu_f(val);
                } else if (EPI == 2) {
                    val = gelu_f(val) * wgt[(size_t)(grow0 + lrow) * 16 + (col >> 6)];
                    Cb[oidx] = (bf16_t)val;
                } else {  // EPI == 3
                    if ((crow & 8191) >= idv) {
                        if (isbf) Cb[oidx] = (bf16_t)((float)Cb[oidx] + val);
                        else      Cf[oidx] = Cf[oidx] + val;
                    }
                }
            }
        }
    }
}

// ---------------------------------------------------------------------------
extern "C" void kernel_launch(void* const* d_in, const int* in_sizes, int n_in,
                              void* d_out, int out_size, void* d_ws, size_t ws_size,
                              hipStream_t stream)
{
    const void* x   = d_in[0];
    const int*  idp = (const int*)d_in[1];
    const void* W1  = d_in[2];
    const void* b1  = d_in[3];
    const void* W2  = d_in[4];
    const void* b2  = d_in[5];
    const void* Wg1 = d_in[6];
    const void* Wa1 = d_in[7];
    const void* Wb1 = d_in[8];
    const void* Wg2 = d_in[9];
    const void* Wa2 = d_in[10];
    const void* Wb2 = d_in[11];

    char* p = (char*)d_ws;
    bf16_t* W1t  = (bf16_t*)(p);                 // 2 MB
    bf16_t* W2t  = (bf16_t*)(p + 2097152);       // 2 MB
    bf16_t* Wat  = (bf16_t*)(p + 4194304);       // 1 MB
    bf16_t* Wbt  = (bf16_t*)(p + 5242880);       // 1 MB
    float*  wbuf = (float*) (p + 6291456);       // 1 MB
    int*    flagp= (int*)   (p + 7340032);       // 64 KB slot
    bf16_t* xb   = (bf16_t*)(p + 7405568);       // 32 MB bf16 x
    bf16_t* big  = (bf16_t*)(p + 40960000);      // h / moeh

    const size_t base = 40960000ull;
    size_t cap = (ws_size > base) ? ws_size - base : 0;
    int Mc = 32768;                               // FFN h chunk [Mc,2048] bf16
    while ((size_t)Mc * 4096ull > cap && Mc > 128) Mc >>= 1;
    int Mcm = 16384;                              // MoE h chunk [Mcm,1024] bf16
    while ((size_t)Mcm * 2048ull > cap && Mcm > 128) Mcm >>= 1;

    detect_kernel<<<1, 256, 0, stream>>>((const unsigned int*)x, flagp);
    convert_kernel<<<8192, 256, 0, stream>>>(x, flagp, xb);
    pack_kernel<<<12288, 256, 0, stream>>>(W1, W2, Wa1, Wa2, Wb1, Wb2, flagp,
                                           W1t, W2t, Wat, Wbt);
    gate_kernel<<<256, 256, 0, stream>>>(x, Wg1, Wg2, flagp, wbuf);

    // FFN, chunked over rows: out[m:m+Mc] = gelu(x@W1+b1)@W2 + b2
    for (int m = 0; m < 32768; m += Mc) {
        gemm_kernel<1, 0><<<dim3(Mc / 128, 16), 256, 0, stream>>>(
            xb, 512, W1t, 512, big, 2048, 512, m, 0,
            b1, nullptr, nullptr, flagp);
        gemm_kernel<0, 0><<<dim3(Mc / 128, 4), 256, 0, stream>>>(
            big, 2048, W2t, 2048, d_out, 512, 2048, 0, m,
            b2, nullptr, nullptr, flagp);
    }
    // MoE, chunked over masked rows: out[map(g)] += (gelu(x@Wa)*w)@Wb
    for (int m = 0; m < 16384; m += Mcm) {
        gemm_kernel<2, 1><<<dim3(Mcm / 128, 8), 256, 0, stream>>>(
            xb, 512, Wat, 512, big, 1024, 512, m, 0,
            nullptr, wbuf, nullptr, flagp);
        gemm_kernel<3, 2><<<dim3(Mcm / 128, 4), 256, 0, stream>>>(
            big, 1024, Wbt, 1024, d_out, 512, 1024, m, 0,
            nullptr, nullptr, idp, flagp);
    }
}